// Round 7
// baseline (330.345 us; speedup 1.0000x reference)
//
#include <hip/hip_runtime.h>

// MemoryBank contrastive loss, steady state.
// B=1024, D=128, C=50, K=4096, N = C*K = 204800. TEMP=0.3.
// loss = (1/B) * sum_b w_b * ( ln(sum exp(dot/T)) - dot_pos/T )
// SCALE = log2(e)/T folded into normalized bf16 features: MFMA acc feeds exp2.
//
// R11: 32 waves/CU WITHIN the observed 2-blocks/CU cap. Evidence across
// R5-R10: every config ran at exactly 2 workgroups/CU regardless of block
// size (256/512 thr) or LDS (32/64 KB) -- R10's nominal 4/CU gave occupancy
// 36% (=R7) and FETCH doubled 52->104 MB (y=2,3 ran as a second round, no
// dedupe). Residency lever is therefore waves-per-block, not blocks-per-CU:
// 1024-thr blocks (16 waves x 32 m-rows = 512 rows/block), 2 blocks/CU =
// 32 waves/CU = 100% thread occupancy. Grid (256,2) = 512 blocks = exactly
// 2/CU, all co-resident in ONE round; y-partners both resident -> FETCH
// ~52 MB; 256%8=0 -> partners share an XCD. nt = 13 (xc<128) / 12.
// Per-wave hot loop is R7's proven code (mf=2, fragment-linear bf16 LDS,
// 0 conflicts, pack-once, T14 split); staging simplifies to ONE 32 B fp32
// chunk -> one 16 B LDS slot per thread. launch_bounds(1024,8) caps VGPR
// at 64 (current 52). LDS traffic invariant to grouping: 1.64 GB total.

#define XCHUNK 256
#define NTILES 3200        // 204800 rows / 64 rows per tile
#define TILE_BYTES 32768   // 64 rows x 128 fp32
#define LN2f 0.6931471805599453f
#define SCALEf 4.808983469629878f   // log2(e)/0.3

typedef __attribute__((ext_vector_type(8))) short bf16x8;
typedef __attribute__((ext_vector_type(4))) float f32x4;
typedef unsigned int u32;

__device__ __forceinline__ unsigned short f2bf(float x) {
    union { float f; unsigned int u; } c; c.f = x;
    unsigned int u = c.u;
    u = (u + 0x7fffu + ((u >> 16) & 1u)) >> 16;   // RNE (features only)
    return (unsigned short)u;
}
__device__ __forceinline__ float bf2f(unsigned short h) {
    union { unsigned int u; float f; } c; c.u = ((unsigned int)h) << 16;
    return c.f;
}
// two fp32 -> two bf16 (truncation) in one v_perm_b32: [bf(lo) | bf(hi)<<16]
__device__ __forceinline__ unsigned int pack_bf2(float lo, float hi) {
    union { float f; unsigned int u; } a, b; a.f = lo; b.f = hi;
    return __builtin_amdgcn_perm(b.u, a.u, 0x07060302u);
}

// ---- Kernel 1: normalize+scale features -> bf16; zero S and out -------------
__global__ void normalize_feat(const float* __restrict__ f,
                               unsigned short* __restrict__ featb,
                               float* __restrict__ S,
                               float* __restrict__ out) {
    const int b = blockIdx.x;          // 1024 blocks
    const int t = threadIdx.x;         // 128 threads
    if (t == 0) S[b] = 0.0f;
    if (b == 0 && t == 1) *out = 0.0f;
    float v = f[b * 128 + t];
    float ss = v * v;
    #pragma unroll
    for (int m = 1; m < 64; m <<= 1) ss += __shfl_xor(ss, m, 64);
    __shared__ float wsum[2];
    if ((t & 63) == 0) wsum[t >> 6] = ss;
    __syncthreads();
    float tot = wsum[0] + wsum[1];
    float inv = SCALEf / fmaxf(sqrtf(tot), 1e-12f);
    featb[b * 128 + t] = f2bf(v * inv);
}

// ---- Kernel 2: fused GEMM + exp2-sum ----------------------------------------
// 1024 thr = 16 waves; wave owns 32 m-rows (mf=2), n-tile 64, K=128 complete.
__global__ __launch_bounds__(1024, 8) void gemm_lse(
        const unsigned short* __restrict__ featb,  // [1024][128] bf16 (scaled)
        const float* __restrict__ mem,             // [204800][128] fp32
        float* __restrict__ S)                     // [1024] exp2-sums
{
    // 2 x 16 KB bf16 tiles, fragment-linear: slot (nf*4+ks)*64 + lane, 16 B each
    __shared__ uint4 ldsb[2][1024];

    const int tid  = threadIdx.x;
    const int wave = tid >> 6;        // 0..15
    const int lane = tid & 63;
    const int col  = lane & 15;
    const int quad = lane >> 4;

    const int m_wave = blockIdx.y * 512 + wave * 32;
    const int xc = blockIdx.x;        // 0..255
    // 3200 = 256*12 + 128: blocks xc<128 process 13 tiles, others 12
    const int nt = (xc < (NTILES - XCHUNK * 12)) ? 13 : 12;

    // A fragments: A[m=col][k=quad*8+j], mf=2 x ks=4 (32 VGPR)
    bf16x8 afrag[2][4];
    #pragma unroll
    for (int mf = 0; mf < 2; ++mf)
        #pragma unroll
        for (int ks = 0; ks < 4; ++ks)
            afrag[mf][ks] = *(const bf16x8*)&featb[(size_t)(m_wave + mf * 16 + col) * 128
                                                   + ks * 32 + quad * 8];

    float s_part[8];
    #pragma unroll
    for (int i = 0; i < 8; ++i) s_part[i] = 0.0f;

    // Tile-invariant global byte offset for this thread's single 32 B fp32
    // chunk. Thread t fills LDS slot t (lane-linear write); the permutation
    // lives on the GLOBAL side: slot -> (nf,ks,quad,col) ->
    // row (nf*16+col), k-bytes ks*128+quad*32.
    int o;
    {
        int Fi = tid >> 6, L = tid & 63;  // fragment id, lane within fragment
        int snf = Fi >> 2, sks = Fi & 3, sq = L >> 4, sc = L & 15;
        o = (snf * 16 + sc) * 512 + sks * 128 + sq * 32;
    }

    // staged registers: 32 B fp32 in flight across COMPUTE (8 VGPR)
    float4 g0a, g0b;

    #define LOADS(t_) {                                                         \
        const char* gt = (const char*)mem + (size_t)(xc + XCHUNK * (t_)) * TILE_BYTES; \
        g0a = *(const float4*)(gt + o);                                         \
        g0b = *(const float4*)(gt + o + 16); }

    #define PACKWRITE(bi) {                                                     \
        uint4 pk;                                                               \
        pk.x = pack_bf2(g0a.x, g0a.y); pk.y = pack_bf2(g0a.z, g0a.w);           \
        pk.z = pack_bf2(g0b.x, g0b.y); pk.w = pack_bf2(g0b.z, g0b.w);           \
        ldsb[bi][tid] = pk; }

    #define COMPUTE(bi) {                                                       \
        _Pragma("unroll")                                                       \
        for (int nf = 0; nf < 4; ++nf) {                                        \
            f32x4 acc[2];                                                       \
            _Pragma("unroll")                                                   \
            for (int mf = 0; mf < 2; ++mf) acc[mf] = (f32x4)(0.0f);             \
            _Pragma("unroll")                                                   \
            for (int ks = 0; ks < 4; ++ks) {                                    \
                bf16x8 bfrag = *(const bf16x8*)&ldsb[bi][(nf * 4 + ks) * 64 + lane]; \
                _Pragma("unroll")                                               \
                for (int mf = 0; mf < 2; ++mf)                                  \
                    acc[mf] = __builtin_amdgcn_mfma_f32_16x16x32_bf16(          \
                        afrag[mf][ks], bfrag, acc[mf], 0, 0, 0);                \
            }                                                                   \
            _Pragma("unroll")                                                   \
            for (int mf = 0; mf < 2; ++mf)                                      \
                _Pragma("unroll")                                               \
                for (int r = 0; r < 4; ++r)                                     \
                    s_part[mf * 4 + r] += __builtin_amdgcn_exp2f(acc[mf][r]);   \
        } }

    // prologue: stage tile 0 into buf0
    LOADS(0)
    PACKWRITE(0)
    __syncthreads();

    for (int t = 0; t < nt; ++t) {
        if (t + 1 < nt) LOADS(t + 1)          // in flight during compute
        COMPUTE(t & 1)
        if (t + 1 < nt) PACKWRITE((t + 1) & 1)     // other buffer; last read 2 barriers ago
        __syncthreads();
    }

    // reduce across the 16 col-lanes sharing the same quad
    #pragma unroll
    for (int d = 1; d < 16; d <<= 1)
        #pragma unroll
        for (int i = 0; i < 8; ++i)
            s_part[i] += __shfl_xor(s_part[i], d, 64);

    if (col == 0) {
        #pragma unroll
        for (int i = 0; i < 8; ++i) {
            int row = m_wave + (i >> 2) * 16 + quad * 4 + (i & 3);
            atomicAdd(&S[row], s_part[i]);
        }
    }
    #undef LOADS
    #undef PACKWRITE
    #undef COMPUTE
}

// ---- Kernel 3: pos logit + weighted mean ------------------------------------
__global__ void finalize_k(const unsigned short* __restrict__ featb,
                           const float* __restrict__ mem,
                           const int* __restrict__ labels,
                           const float* __restrict__ S,
                           float* __restrict__ out) {
    const int wave = threadIdx.x >> 6;
    const int lane = threadIdx.x & 63;
    const int b = blockIdx.x * 4 + wave;          // 256 blocks x 4 waves = 1024
    const int lab = labels[b];
    const float* mrow = mem + (size_t)lab * (4096 * 128);   // memory[lab][0][:]
    float fa = bf2f(featb[b * 128 + lane]);
    float fc = bf2f(featb[b * 128 + lane + 64]);
    float p = fa * mrow[lane] + fc * mrow[lane + 64];       // t_pos (log2 domain)
    #pragma unroll
    for (int m = 1; m < 64; m <<= 1) p += __shfl_xor(p, m, 64);
    if (lane == 0) {
        float w = (lab < 2) ? 1.3f : 1.0f;
        float v = w * LN2f * (log2f(S[b]) - p) * (1.0f / 1024.0f);
        atomicAdd(out, v);
    }
}

extern "C" void kernel_launch(void* const* d_in, const int* in_sizes, int n_in,
                              void* d_out, int out_size, void* d_ws, size_t ws_size,
                              hipStream_t stream) {
    const float* features = (const float*)d_in[0];
    const int*   labels   = (const int*)d_in[1];
    const float* memory   = (const float*)d_in[2];
    float* out = (float*)d_out;

    unsigned short* featb = (unsigned short*)d_ws;               // 256 KiB
    float* S = (float*)((char*)d_ws + 1024 * 128 * 2);           // 1024 floats

    normalize_feat<<<1024, 128, 0, stream>>>(features, featb, S, out);
    gemm_lse<<<dim3(XCHUNK, 2), 1024, 0, stream>>>(featb, memory, S);
    finalize_k<<<256, 256, 0, stream>>>(featb, memory, labels, S, out);
}

// Round 8
// 241.031 us; speedup vs baseline: 1.3706x; 1.3706x over previous
//
#include <hip/hip_runtime.h>

// MemoryBank contrastive loss, steady state.
// B=1024, D=128, C=50, K=4096, N = C*K = 204800. TEMP=0.3.
// loss = (1/B) * sum_b w_b * ( ln(sum exp(dot/T)) - dot_pos/T )
// SCALE = log2(e)/T folded into normalized bf16 features: MFMA acc feeds exp2.
//
// R12: the "2 blocks/CU cap" was launch_bounds all along. Residency tracked
// arg2 exactly in EVERY round: (256,2)/(512,2)->8 waves/CU (R5/R6/R8, occ
// 19%), (512,4)->16 (R7/R10, occ 37%; R10's grid-for-4 still ran 2 rounds),
// (1024,8)->32 (R11, occ 74% -- but its 64-reg cap spilled the ~70-reg
// loop: VGPR 32, WRITE 130 MB). arg2 pins waves/EU as a CAP in this
// toolchain. Fix: NO launch_bounds on gemm_lse -- allocator unconstrained
// (no spill), residency resource-determined: VGPR ~52-60 -> 8 waves/EU;
// LDS 4x32=128<=160 KB; threads 4x512=2048=cap -> 4 blocks/CU = 32
// waves/CU. Grid (256,4) = 1024 blocks, ALL co-resident in one round;
// all 4 y-partners of each xc resident -> L3 dedupe (FETCH ~52 MB is the
// check; ~104 MB + occ ~37 falsifies the cap hypothesis). nt = 13/12
// (3200 = 256*12.5). Hot loop is R7's proven code: mf=2 (32 rows/wave),
// fragment-linear bf16 LDS (0 conflicts, pack-once), T14 split (loads t+1
// in flight across COMPUTE(t), pack+write after).

#define XCHUNK 256
#define NTILES 3200        // 204800 rows / 64 rows per tile
#define TILE_BYTES 32768   // 64 rows x 128 fp32
#define LN2f 0.6931471805599453f
#define SCALEf 4.808983469629878f   // log2(e)/0.3

typedef __attribute__((ext_vector_type(8))) short bf16x8;
typedef __attribute__((ext_vector_type(4))) float f32x4;
typedef unsigned int u32;

__device__ __forceinline__ unsigned short f2bf(float x) {
    union { float f; unsigned int u; } c; c.f = x;
    unsigned int u = c.u;
    u = (u + 0x7fffu + ((u >> 16) & 1u)) >> 16;   // RNE (features only)
    return (unsigned short)u;
}
__device__ __forceinline__ float bf2f(unsigned short h) {
    union { unsigned int u; float f; } c; c.u = ((unsigned int)h) << 16;
    return c.f;
}
// two fp32 -> two bf16 (truncation) in one v_perm_b32: [bf(lo) | bf(hi)<<16]
__device__ __forceinline__ unsigned int pack_bf2(float lo, float hi) {
    union { float f; unsigned int u; } a, b; a.f = lo; b.f = hi;
    return __builtin_amdgcn_perm(b.u, a.u, 0x07060302u);
}

// ---- Kernel 1: normalize+scale features -> bf16; zero S and out -------------
__global__ void normalize_feat(const float* __restrict__ f,
                               unsigned short* __restrict__ featb,
                               float* __restrict__ S,
                               float* __restrict__ out) {
    const int b = blockIdx.x;          // 1024 blocks
    const int t = threadIdx.x;         // 128 threads
    if (t == 0) S[b] = 0.0f;
    if (b == 0 && t == 1) *out = 0.0f;
    float v = f[b * 128 + t];
    float ss = v * v;
    #pragma unroll
    for (int m = 1; m < 64; m <<= 1) ss += __shfl_xor(ss, m, 64);
    __shared__ float wsum[2];
    if ((t & 63) == 0) wsum[t >> 6] = ss;
    __syncthreads();
    float tot = wsum[0] + wsum[1];
    float inv = SCALEf / fmaxf(sqrtf(tot), 1e-12f);
    featb[b * 128 + t] = f2bf(v * inv);
}

// ---- Kernel 2: fused GEMM + exp2-sum ----------------------------------------
// 512 thr = 8 waves; wave owns 32 m-rows (mf=2), n-tile 64, K=128 complete.
// NO __launch_bounds__: arg2 pins waves/EU as a cap in this toolchain (see
// header). Natural VGPR ~52-60 -> 8 waves/EU -> 4 blocks/CU resident.
__global__ void gemm_lse(
        const unsigned short* __restrict__ featb,  // [1024][128] bf16 (scaled)
        const float* __restrict__ mem,             // [204800][128] fp32
        float* __restrict__ S)                     // [1024] exp2-sums
{
    // 2 x 16 KB bf16 tiles, fragment-linear: slot (nf*4+ks)*64 + lane, 16 B each
    __shared__ uint4 ldsb[2][1024];

    const int tid  = threadIdx.x;
    const int wave = tid >> 6;        // 0..7
    const int lane = tid & 63;
    const int col  = lane & 15;
    const int quad = lane >> 4;

    const int m_wave = blockIdx.y * 256 + wave * 32;
    const int xc = blockIdx.x;        // 0..255
    // 3200 = 256*12 + 128: blocks xc<128 process 13 tiles, others 12
    const int nt = (xc < (NTILES - XCHUNK * 12)) ? 13 : 12;

    // A fragments: A[m=col][k=quad*8+j], mf=2 x ks=4 (32 VGPR)
    bf16x8 afrag[2][4];
    #pragma unroll
    for (int mf = 0; mf < 2; ++mf)
        #pragma unroll
        for (int ks = 0; ks < 4; ++ks)
            afrag[mf][ks] = *(const bf16x8*)&featb[(size_t)(m_wave + mf * 16 + col) * 128
                                                   + ks * 32 + quad * 8];

    float s_part[8];
    #pragma unroll
    for (int i = 0; i < 8; ++i) s_part[i] = 0.0f;

    // Tile-invariant global byte offsets for this thread's two 32 B fp32
    // chunks. Thread t fills LDS slots {t, 512+t} (lane-linear writes); the
    // permutation lives on the GLOBAL side: slot -> (nf,ks,quad,col) ->
    // row (nf*16+col), k-bytes ks*128+quad*32.
    int o[2];
    #pragma unroll
    for (int j = 0; j < 2; ++j) {
        int Sl = j * 512 + tid;           // slot index 0..1023
        int Fi = Sl >> 6, L = Sl & 63;    // fragment id, lane within fragment
        int snf = Fi >> 2, sks = Fi & 3, sq = L >> 4, sc = L & 15;
        o[j] = (snf * 16 + sc) * 512 + sks * 128 + sq * 32;
    }

    // staged registers: 64 B fp32 in flight across COMPUTE (16 VGPR)
    float4 g0a, g0b, g1a, g1b;

    #define LOADS(t_) {                                                         \
        const char* gt = (const char*)mem + (size_t)(xc + XCHUNK * (t_)) * TILE_BYTES; \
        g0a = *(const float4*)(gt + o[0]);                                      \
        g0b = *(const float4*)(gt + o[0] + 16);                                 \
        g1a = *(const float4*)(gt + o[1]);                                      \
        g1b = *(const float4*)(gt + o[1] + 16); }

    #define PACKWRITE(bi) {                                                     \
        uint4 pk;                                                               \
        pk.x = pack_bf2(g0a.x, g0a.y); pk.y = pack_bf2(g0a.z, g0a.w);           \
        pk.z = pack_bf2(g0b.x, g0b.y); pk.w = pack_bf2(g0b.z, g0b.w);           \
        ldsb[bi][tid] = pk;                                                     \
        pk.x = pack_bf2(g1a.x, g1a.y); pk.y = pack_bf2(g1a.z, g1a.w);           \
        pk.z = pack_bf2(g1b.x, g1b.y); pk.w = pack_bf2(g1b.z, g1b.w);           \
        ldsb[bi][512 + tid] = pk; }

    #define COMPUTE(bi) {                                                       \
        _Pragma("unroll")                                                       \
        for (int nf = 0; nf < 4; ++nf) {                                        \
            f32x4 acc[2];                                                       \
            _Pragma("unroll")                                                   \
            for (int mf = 0; mf < 2; ++mf) acc[mf] = (f32x4)(0.0f);             \
            _Pragma("unroll")                                                   \
            for (int ks = 0; ks < 4; ++ks) {                                    \
                bf16x8 bfrag = *(const bf16x8*)&ldsb[bi][(nf * 4 + ks) * 64 + lane]; \
                _Pragma("unroll")                                               \
                for (int mf = 0; mf < 2; ++mf)                                  \
                    acc[mf] = __builtin_amdgcn_mfma_f32_16x16x32_bf16(          \
                        afrag[mf][ks], bfrag, acc[mf], 0, 0, 0);                \
            }                                                                   \
            _Pragma("unroll")                                                   \
            for (int mf = 0; mf < 2; ++mf)                                      \
                _Pragma("unroll")                                               \
                for (int r = 0; r < 4; ++r)                                     \
                    s_part[mf * 4 + r] += __builtin_amdgcn_exp2f(acc[mf][r]);   \
        } }

    // prologue: stage tile 0 into buf0
    LOADS(0)
    PACKWRITE(0)
    __syncthreads();

    for (int t = 0; t < nt; ++t) {
        if (t + 1 < nt) LOADS(t + 1)          // in flight during compute
        COMPUTE(t & 1)
        if (t + 1 < nt) PACKWRITE((t + 1) & 1)     // other buffer; last read 2 barriers ago
        __syncthreads();
    }

    // reduce across the 16 col-lanes sharing the same quad
    #pragma unroll
    for (int d = 1; d < 16; d <<= 1)
        #pragma unroll
        for (int i = 0; i < 8; ++i)
            s_part[i] += __shfl_xor(s_part[i], d, 64);

    if (col == 0) {
        #pragma unroll
        for (int i = 0; i < 8; ++i) {
            int row = m_wave + (i >> 2) * 16 + quad * 4 + (i & 3);
            atomicAdd(&S[row], s_part[i]);
        }
    }
    #undef LOADS
    #undef PACKWRITE
    #undef COMPUTE
}

// ---- Kernel 3: pos logit + weighted mean ------------------------------------
__global__ void finalize_k(const unsigned short* __restrict__ featb,
                           const float* __restrict__ mem,
                           const int* __restrict__ labels,
                           const float* __restrict__ S,
                           float* __restrict__ out) {
    const int wave = threadIdx.x >> 6;
    const int lane = threadIdx.x & 63;
    const int b = blockIdx.x * 4 + wave;          // 256 blocks x 4 waves = 1024
    const int lab = labels[b];
    const float* mrow = mem + (size_t)lab * (4096 * 128);   // memory[lab][0][:]
    float fa = bf2f(featb[b * 128 + lane]);
    float fc = bf2f(featb[b * 128 + lane + 64]);
    float p = fa * mrow[lane] + fc * mrow[lane + 64];       // t_pos (log2 domain)
    #pragma unroll
    for (int m = 1; m < 64; m <<= 1) p += __shfl_xor(p, m, 64);
    if (lane == 0) {
        float w = (lab < 2) ? 1.3f : 1.0f;
        float v = w * LN2f * (log2f(S[b]) - p) * (1.0f / 1024.0f);
        atomicAdd(out, v);
    }
}

extern "C" void kernel_launch(void* const* d_in, const int* in_sizes, int n_in,
                              void* d_out, int out_size, void* d_ws, size_t ws_size,
                              hipStream_t stream) {
    const float* features = (const float*)d_in[0];
    const int*   labels   = (const int*)d_in[1];
    const float* memory   = (const float*)d_in[2];
    float* out = (float*)d_out;

    unsigned short* featb = (unsigned short*)d_ws;               // 256 KiB
    float* S = (float*)((char*)d_ws + 1024 * 128 * 2);           // 1024 floats

    normalize_feat<<<1024, 128, 0, stream>>>(features, featb, S, out);
    gemm_lse<<<dim3(XCHUNK, 4), 512, 0, stream>>>(featb, memory, S);
    finalize_k<<<256, 256, 0, stream>>>(featb, memory, labels, S, out);
}

// Round 9
// 240.484 us; speedup vs baseline: 1.3737x; 1.0023x over previous
//
#include <hip/hip_runtime.h>

// MemoryBank contrastive loss, steady state.
// B=1024, D=128, C=50, K=4096, N = C*K = 204800. TEMP=0.3.
// loss = (1/B) * sum_b w_b * ( ln(sum exp(dot/T)) - dot_pos/T )
// SCALE = log2(e)/T folded into normalized bf16 features: MFMA acc feeds exp2.
//
// R13 = R11 minus the register cap. Cross-round evidence: residency is
// ALWAYS 2 workgroups/CU (R5-R12, incl. R12's no-bounds control: occ 37%,
// FETCH 104 MB) -- likely coarse LDS granule (32 KB request ~ 64 KB).
// The only lever that moved occupancy is waves-per-block: 1024-thr blocks
// (R11) hit 74%. R11's 205 us came solely from launch_bounds(1024,8)'s
// 64-reg cap spilling a ~70-reg loop (VGPR 32, WRITE 130 MB, FETCH 468 MB);
// R12 proved the same loop allocates 52 VGPR spill-free unconstrained.
// So: 16 waves x 1024 thr, NO launch_bounds, grid (256,2) = 512 blocks =
// 2/CU, ALL co-resident in one round (y-partners resident -> L3 dedupe,
// FETCH ~52 MB check; WRITE ~2 MB and VGPR ~52 are the no-spill checks).
// nt = 13 (xc<128) / 12. Hot loop: mf=2 (32 rows/wave), fragment-linear
// bf16 LDS (0 conflicts, pack-once), T14 split, one 32 B chunk/thread.

#define XCHUNK 256
#define NTILES 3200        // 204800 rows / 64 rows per tile
#define TILE_BYTES 32768   // 64 rows x 128 fp32
#define LN2f 0.6931471805599453f
#define SCALEf 4.808983469629878f   // log2(e)/0.3

typedef __attribute__((ext_vector_type(8))) short bf16x8;
typedef __attribute__((ext_vector_type(4))) float f32x4;
typedef unsigned int u32;

__device__ __forceinline__ unsigned short f2bf(float x) {
    union { float f; unsigned int u; } c; c.f = x;
    unsigned int u = c.u;
    u = (u + 0x7fffu + ((u >> 16) & 1u)) >> 16;   // RNE (features only)
    return (unsigned short)u;
}
__device__ __forceinline__ float bf2f(unsigned short h) {
    union { unsigned int u; float f; } c; c.u = ((unsigned int)h) << 16;
    return c.f;
}
// two fp32 -> two bf16 (truncation) in one v_perm_b32: [bf(lo) | bf(hi)<<16]
__device__ __forceinline__ unsigned int pack_bf2(float lo, float hi) {
    union { float f; unsigned int u; } a, b; a.f = lo; b.f = hi;
    return __builtin_amdgcn_perm(b.u, a.u, 0x07060302u);
}

// ---- Kernel 1: normalize+scale features -> bf16; zero S and out -------------
__global__ void normalize_feat(const float* __restrict__ f,
                               unsigned short* __restrict__ featb,
                               float* __restrict__ S,
                               float* __restrict__ out) {
    const int b = blockIdx.x;          // 1024 blocks
    const int t = threadIdx.x;         // 128 threads
    if (t == 0) S[b] = 0.0f;
    if (b == 0 && t == 1) *out = 0.0f;
    float v = f[b * 128 + t];
    float ss = v * v;
    #pragma unroll
    for (int m = 1; m < 64; m <<= 1) ss += __shfl_xor(ss, m, 64);
    __shared__ float wsum[2];
    if ((t & 63) == 0) wsum[t >> 6] = ss;
    __syncthreads();
    float tot = wsum[0] + wsum[1];
    float inv = SCALEf / fmaxf(sqrtf(tot), 1e-12f);
    featb[b * 128 + t] = f2bf(v * inv);
}

// ---- Kernel 2: fused GEMM + exp2-sum ----------------------------------------
// 1024 thr = 16 waves; wave owns 32 m-rows (mf=2), n-tile 64, K=128 complete.
// NO __launch_bounds__: R11's (1024,8) imposed a 64-reg cap -> spill; the
// natural allocation for this loop is ~52 VGPR (measured R12), spill-free.
__global__ void gemm_lse(
        const unsigned short* __restrict__ featb,  // [1024][128] bf16 (scaled)
        const float* __restrict__ mem,             // [204800][128] fp32
        float* __restrict__ S)                     // [1024] exp2-sums
{
    // 2 x 16 KB bf16 tiles, fragment-linear: slot (nf*4+ks)*64 + lane, 16 B each
    __shared__ uint4 ldsb[2][1024];

    const int tid  = threadIdx.x;
    const int wave = tid >> 6;        // 0..15
    const int lane = tid & 63;
    const int col  = lane & 15;
    const int quad = lane >> 4;

    const int m_wave = blockIdx.y * 512 + wave * 32;
    const int xc = blockIdx.x;        // 0..255
    // 3200 = 256*12 + 128: blocks xc<128 process 13 tiles, others 12
    const int nt = (xc < (NTILES - XCHUNK * 12)) ? 13 : 12;

    // A fragments: A[m=col][k=quad*8+j], mf=2 x ks=4 (32 VGPR)
    bf16x8 afrag[2][4];
    #pragma unroll
    for (int mf = 0; mf < 2; ++mf)
        #pragma unroll
        for (int ks = 0; ks < 4; ++ks)
            afrag[mf][ks] = *(const bf16x8*)&featb[(size_t)(m_wave + mf * 16 + col) * 128
                                                   + ks * 32 + quad * 8];

    float s_part[8];
    #pragma unroll
    for (int i = 0; i < 8; ++i) s_part[i] = 0.0f;

    // Tile-invariant global byte offset for this thread's single 32 B fp32
    // chunk. Thread t fills LDS slot t (lane-linear write); the permutation
    // lives on the GLOBAL side: slot -> (nf,ks,quad,col) ->
    // row (nf*16+col), k-bytes ks*128+quad*32.
    int o;
    {
        int Fi = tid >> 6, L = tid & 63;  // fragment id, lane within fragment
        int snf = Fi >> 2, sks = Fi & 3, sq = L >> 4, sc = L & 15;
        o = (snf * 16 + sc) * 512 + sks * 128 + sq * 32;
    }

    // staged registers: 32 B fp32 in flight across COMPUTE (8 VGPR)
    float4 g0a, g0b;

    #define LOADS(t_) {                                                         \
        const char* gt = (const char*)mem + (size_t)(xc + XCHUNK * (t_)) * TILE_BYTES; \
        g0a = *(const float4*)(gt + o);                                         \
        g0b = *(const float4*)(gt + o + 16); }

    #define PACKWRITE(bi) {                                                     \
        uint4 pk;                                                               \
        pk.x = pack_bf2(g0a.x, g0a.y); pk.y = pack_bf2(g0a.z, g0a.w);           \
        pk.z = pack_bf2(g0b.x, g0b.y); pk.w = pack_bf2(g0b.z, g0b.w);           \
        ldsb[bi][tid] = pk; }

    #define COMPUTE(bi) {                                                       \
        _Pragma("unroll")                                                       \
        for (int nf = 0; nf < 4; ++nf) {                                        \
            f32x4 acc[2];                                                       \
            _Pragma("unroll")                                                   \
            for (int mf = 0; mf < 2; ++mf) acc[mf] = (f32x4)(0.0f);             \
            _Pragma("unroll")                                                   \
            for (int ks = 0; ks < 4; ++ks) {                                    \
                bf16x8 bfrag = *(const bf16x8*)&ldsb[bi][(nf * 4 + ks) * 64 + lane]; \
                _Pragma("unroll")                                               \
                for (int mf = 0; mf < 2; ++mf)                                  \
                    acc[mf] = __builtin_amdgcn_mfma_f32_16x16x32_bf16(          \
                        afrag[mf][ks], bfrag, acc[mf], 0, 0, 0);                \
            }                                                                   \
            _Pragma("unroll")                                                   \
            for (int mf = 0; mf < 2; ++mf)                                      \
                _Pragma("unroll")                                               \
                for (int r = 0; r < 4; ++r)                                     \
                    s_part[mf * 4 + r] += __builtin_amdgcn_exp2f(acc[mf][r]);   \
        } }

    // prologue: stage tile 0 into buf0
    LOADS(0)
    PACKWRITE(0)
    __syncthreads();

    for (int t = 0; t < nt; ++t) {
        if (t + 1 < nt) LOADS(t + 1)          // in flight during compute
        COMPUTE(t & 1)
        if (t + 1 < nt) PACKWRITE((t + 1) & 1)     // other buffer; last read 2 barriers ago
        __syncthreads();
    }

    // reduce across the 16 col-lanes sharing the same quad
    #pragma unroll
    for (int d = 1; d < 16; d <<= 1)
        #pragma unroll
        for (int i = 0; i < 8; ++i)
            s_part[i] += __shfl_xor(s_part[i], d, 64);

    if (col == 0) {
        #pragma unroll
        for (int i = 0; i < 8; ++i) {
            int row = m_wave + (i >> 2) * 16 + quad * 4 + (i & 3);
            atomicAdd(&S[row], s_part[i]);
        }
    }
    #undef LOADS
    #undef PACKWRITE
    #undef COMPUTE
}

// ---- Kernel 3: pos logit + weighted mean ------------------------------------
__global__ void finalize_k(const unsigned short* __restrict__ featb,
                           const float* __restrict__ mem,
                           const int* __restrict__ labels,
                           const float* __restrict__ S,
                           float* __restrict__ out) {
    const int wave = threadIdx.x >> 6;
    const int lane = threadIdx.x & 63;
    const int b = blockIdx.x * 4 + wave;          // 256 blocks x 4 waves = 1024
    const int lab = labels[b];
    const float* mrow = mem + (size_t)lab * (4096 * 128);   // memory[lab][0][:]
    float fa = bf2f(featb[b * 128 + lane]);
    float fc = bf2f(featb[b * 128 + lane + 64]);
    float p = fa * mrow[lane] + fc * mrow[lane + 64];       // t_pos (log2 domain)
    #pragma unroll
    for (int m = 1; m < 64; m <<= 1) p += __shfl_xor(p, m, 64);
    if (lane == 0) {
        float w = (lab < 2) ? 1.3f : 1.0f;
        float v = w * LN2f * (log2f(S[b]) - p) * (1.0f / 1024.0f);
        atomicAdd(out, v);
    }
}

extern "C" void kernel_launch(void* const* d_in, const int* in_sizes, int n_in,
                              void* d_out, int out_size, void* d_ws, size_t ws_size,
                              hipStream_t stream) {
    const float* features = (const float*)d_in[0];
    const int*   labels   = (const int*)d_in[1];
    const float* memory   = (const float*)d_in[2];
    float* out = (float*)d_out;

    unsigned short* featb = (unsigned short*)d_ws;               // 256 KiB
    float* S = (float*)((char*)d_ws + 1024 * 128 * 2);           // 1024 floats

    normalize_feat<<<1024, 128, 0, stream>>>(features, featb, S, out);
    gemm_lse<<<dim3(XCHUNK, 2), 1024, 0, stream>>>(featb, memory, S);
    finalize_k<<<256, 256, 0, stream>>>(featb, memory, labels, S, out);
}

// Round 10
// 207.279 us; speedup vs baseline: 1.5937x; 1.1602x over previous
//
#include <hip/hip_runtime.h>

// MemoryBank contrastive loss, steady state.
// B=1024, D=128, C=50, K=4096, N = C*K = 204800. TEMP=0.3.
// loss = (1/B) * sum_b w_b * ( ln(sum exp(dot/T)) - dot_pos/T )
// SCALE = log2(e)/T folded into normalized bf16 features: MFMA acc feeds exp2.
//
// R14: overlap the pipes, stop chasing occupancy. R13 closed that arc:
// 1024-thr -> 1 block/CU (occ 38.7), (256,*) grids lose CU-pair dedupe
// (FETCH 104 vs 52 MB). R7 remains best (78.6 us) and its pipe accounting
// is exact: MFMA 26us + LDS-read 31us + VALU/trans 25us ~ 78.6 -- fully
// SERIALIZED (MfmaUtil 27.5% = MFMA at its floor; barrier lockstep +
// per-wave dep chain ds_read->MFMA->exp2 keeps one pipe hot at a time).
// Overlapped ceiling = max(31,26,25) ~ 35us. Fix (T15 pattern): per-nf
// accumulator double-buffer -- defer exp2(acc_nf) one phase, so
// MFMA(nf+1)->accB issues on the matrix pipe WHILE exp2(accA) issues on
// VALU/trans (independent regs, named aA/aB for static indexing). 3/4 of
// exp2 serialization removed + longer dep-free window for ds_read hoist.
// Everything else is R7 verbatim: grid (128,4)=512 blocks 2/CU (CU-pair
// L2 dedupe -> FETCH 52MB), 512 thr, mf=2, NITER=25, fragment-linear bf16
// LDS (0 conflicts, pack-once), T14 split. VGPR ~95-110 < 128 keeps
// 2-block residency; WRITE ~2MB is the no-spill check.

#define XCHUNK 128
#define NITER 25           // 128 * 25 = 3200 tiles of 64 rows = 204800
#define TILE_BYTES 32768   // 64 rows x 128 fp32
#define LN2f 0.6931471805599453f
#define SCALEf 4.808983469629878f   // log2(e)/0.3

typedef __attribute__((ext_vector_type(8))) short bf16x8;
typedef __attribute__((ext_vector_type(4))) float f32x4;
typedef unsigned int u32;

__device__ __forceinline__ unsigned short f2bf(float x) {
    union { float f; unsigned int u; } c; c.f = x;
    unsigned int u = c.u;
    u = (u + 0x7fffu + ((u >> 16) & 1u)) >> 16;   // RNE (features only)
    return (unsigned short)u;
}
__device__ __forceinline__ float bf2f(unsigned short h) {
    union { unsigned int u; float f; } c; c.u = ((unsigned int)h) << 16;
    return c.f;
}
// two fp32 -> two bf16 (truncation) in one v_perm_b32: [bf(lo) | bf(hi)<<16]
__device__ __forceinline__ unsigned int pack_bf2(float lo, float hi) {
    union { float f; unsigned int u; } a, b; a.f = lo; b.f = hi;
    return __builtin_amdgcn_perm(b.u, a.u, 0x07060302u);
}

// ---- Kernel 1: normalize+scale features -> bf16; zero S and out -------------
__global__ void normalize_feat(const float* __restrict__ f,
                               unsigned short* __restrict__ featb,
                               float* __restrict__ S,
                               float* __restrict__ out) {
    const int b = blockIdx.x;          // 1024 blocks
    const int t = threadIdx.x;         // 128 threads
    if (t == 0) S[b] = 0.0f;
    if (b == 0 && t == 1) *out = 0.0f;
    float v = f[b * 128 + t];
    float ss = v * v;
    #pragma unroll
    for (int m = 1; m < 64; m <<= 1) ss += __shfl_xor(ss, m, 64);
    __shared__ float wsum[2];
    if ((t & 63) == 0) wsum[t >> 6] = ss;
    __syncthreads();
    float tot = wsum[0] + wsum[1];
    float inv = SCALEf / fmaxf(sqrtf(tot), 1e-12f);
    featb[b * 128 + t] = f2bf(v * inv);
}

// ---- Kernel 2: fused GEMM + exp2-sum ----------------------------------------
// 512 thr = 8 waves; wave owns 32 m-rows (mf=2), n-tile 64, K=128 complete.
// NO __launch_bounds__: natural allocation, no spill (R12/R13 evidence).
__global__ void gemm_lse(
        const unsigned short* __restrict__ featb,  // [1024][128] bf16 (scaled)
        const float* __restrict__ mem,             // [204800][128] fp32
        float* __restrict__ S)                     // [1024] exp2-sums
{
    // 2 x 16 KB bf16 tiles, fragment-linear: slot (nf*4+ks)*64 + lane, 16 B each
    __shared__ uint4 ldsb[2][1024];

    const int tid  = threadIdx.x;
    const int wave = tid >> 6;        // 0..7
    const int lane = tid & 63;
    const int col  = lane & 15;
    const int quad = lane >> 4;

    const int m_wave = blockIdx.y * 256 + wave * 32;
    const int xc = blockIdx.x;        // 0..127

    // A fragments: A[m=col][k=quad*8+j], mf=2 x ks=4 (32 VGPR)
    bf16x8 afrag[2][4];
    #pragma unroll
    for (int mf = 0; mf < 2; ++mf)
        #pragma unroll
        for (int ks = 0; ks < 4; ++ks)
            afrag[mf][ks] = *(const bf16x8*)&featb[(size_t)(m_wave + mf * 16 + col) * 128
                                                   + ks * 32 + quad * 8];

    float s_part[8];
    #pragma unroll
    for (int i = 0; i < 8; ++i) s_part[i] = 0.0f;

    // Tile-invariant global byte offsets for this thread's two 32 B fp32
    // chunks. Thread t fills LDS slots {t, 512+t} (lane-linear writes); the
    // permutation lives on the GLOBAL side: slot -> (nf,ks,quad,col) ->
    // row (nf*16+col), k-bytes ks*128+quad*32.
    int o[2];
    #pragma unroll
    for (int j = 0; j < 2; ++j) {
        int Sl = j * 512 + tid;           // slot index 0..1023
        int Fi = Sl >> 6, L = Sl & 63;    // fragment id, lane within fragment
        int snf = Fi >> 2, sks = Fi & 3, sq = L >> 4, sc = L & 15;
        o[j] = (snf * 16 + sc) * 512 + sks * 128 + sq * 32;
    }

    // staged registers: 64 B fp32 in flight across COMPUTE (16 VGPR)
    float4 g0a, g0b, g1a, g1b;

    #define LOADS(t_) {                                                         \
        const char* gt = (const char*)mem + (size_t)(xc + XCHUNK * (t_)) * TILE_BYTES; \
        g0a = *(const float4*)(gt + o[0]);                                      \
        g0b = *(const float4*)(gt + o[0] + 16);                                 \
        g1a = *(const float4*)(gt + o[1]);                                      \
        g1b = *(const float4*)(gt + o[1] + 16); }

    #define PACKWRITE(bi) {                                                     \
        uint4 pk;                                                               \
        pk.x = pack_bf2(g0a.x, g0a.y); pk.y = pack_bf2(g0a.z, g0a.w);           \
        pk.z = pack_bf2(g0b.x, g0b.y); pk.w = pack_bf2(g0b.z, g0b.w);           \
        ldsb[bi][tid] = pk;                                                     \
        pk.x = pack_bf2(g1a.x, g1a.y); pk.y = pack_bf2(g1a.z, g1a.w);           \
        pk.z = pack_bf2(g1b.x, g1b.y); pk.w = pack_bf2(g1b.z, g1b.w);           \
        ldsb[bi][512 + tid] = pk; }

    // One nf-phase: 4 ds_reads + 8 MFMA into the named acc pair.
    #define NFBLOCK(bi, nf_, A0, A1) {                                          \
        _Pragma("unroll")                                                       \
        for (int ks = 0; ks < 4; ++ks) {                                        \
            bf16x8 bfrag = *(const bf16x8*)&ldsb[bi][((nf_) * 4 + ks) * 64 + lane]; \
            A0 = __builtin_amdgcn_mfma_f32_16x16x32_bf16(afrag[0][ks], bfrag, A0, 0, 0, 0); \
            A1 = __builtin_amdgcn_mfma_f32_16x16x32_bf16(afrag[1][ks], bfrag, A1, 0, 0, 0); \
        } }

    #define EXPSUM(A0, A1) {                                                    \
        _Pragma("unroll")                                                       \
        for (int r = 0; r < 4; ++r) {                                           \
            s_part[r]     += __builtin_amdgcn_exp2f(A0[r]);                     \
            s_part[4 + r] += __builtin_amdgcn_exp2f(A1[r]);                     \
        } }

    // T15-style phase pipeline: MFMA(nf)->accB while exp2(accA of nf-1)
    // issues on VALU/trans. Named regs (static indexing, rule #20).
    #define COMPUTE(bi) {                                                       \
        f32x4 aA0 = (f32x4)(0.0f), aA1 = (f32x4)(0.0f);                         \
        NFBLOCK(bi, 0, aA0, aA1)                                                \
        f32x4 aB0 = (f32x4)(0.0f), aB1 = (f32x4)(0.0f);                         \
        NFBLOCK(bi, 1, aB0, aB1)                                                \
        EXPSUM(aA0, aA1)                                                        \
        aA0 = (f32x4)(0.0f); aA1 = (f32x4)(0.0f);                               \
        NFBLOCK(bi, 2, aA0, aA1)                                                \
        EXPSUM(aB0, aB1)                                                        \
        aB0 = (f32x4)(0.0f); aB1 = (f32x4)(0.0f);                               \
        NFBLOCK(bi, 3, aB0, aB1)                                                \
        EXPSUM(aA0, aA1)                                                        \
        EXPSUM(aB0, aB1)                                                        \
    }

    // prologue: stage tile 0 into buf0
    LOADS(0)
    PACKWRITE(0)
    __syncthreads();

    for (int t = 0; t < NITER; ++t) {
        if (t + 1 < NITER) LOADS(t + 1)       // in flight during compute
        COMPUTE(t & 1)
        if (t + 1 < NITER) PACKWRITE((t + 1) & 1)  // other buffer; last read 2 barriers ago
        __syncthreads();
    }

    // reduce across the 16 col-lanes sharing the same quad
    #pragma unroll
    for (int d = 1; d < 16; d <<= 1)
        #pragma unroll
        for (int i = 0; i < 8; ++i)
            s_part[i] += __shfl_xor(s_part[i], d, 64);

    if (col == 0) {
        #pragma unroll
        for (int i = 0; i < 8; ++i) {
            int row = m_wave + (i >> 2) * 16 + quad * 4 + (i & 3);
            atomicAdd(&S[row], s_part[i]);
        }
    }
    #undef LOADS
    #undef PACKWRITE
    #undef NFBLOCK
    #undef EXPSUM
    #undef COMPUTE
}

// ---- Kernel 3: pos logit + weighted mean ------------------------------------
__global__ void finalize_k(const unsigned short* __restrict__ featb,
                           const float* __restrict__ mem,
                           const int* __restrict__ labels,
                           const float* __restrict__ S,
                           float* __restrict__ out) {
    const int wave = threadIdx.x >> 6;
    const int lane = threadIdx.x & 63;
    const int b = blockIdx.x * 4 + wave;          // 256 blocks x 4 waves = 1024
    const int lab = labels[b];
    const float* mrow = mem + (size_t)lab * (4096 * 128);   // memory[lab][0][:]
    float fa = bf2f(featb[b * 128 + lane]);
    float fc = bf2f(featb[b * 128 + lane + 64]);
    float p = fa * mrow[lane] + fc * mrow[lane + 64];       // t_pos (log2 domain)
    #pragma unroll
    for (int m = 1; m < 64; m <<= 1) p += __shfl_xor(p, m, 64);
    if (lane == 0) {
        float w = (lab < 2) ? 1.3f : 1.0f;
        float v = w * LN2f * (log2f(S[b]) - p) * (1.0f / 1024.0f);
        atomicAdd(out, v);
    }
}

extern "C" void kernel_launch(void* const* d_in, const int* in_sizes, int n_in,
                              void* d_out, int out_size, void* d_ws, size_t ws_size,
                              hipStream_t stream) {
    const float* features = (const float*)d_in[0];
    const int*   labels   = (const int*)d_in[1];
    const float* memory   = (const float*)d_in[2];
    float* out = (float*)d_out;

    unsigned short* featb = (unsigned short*)d_ws;               // 256 KiB
    float* S = (float*)((char*)d_ws + 1024 * 128 * 2);           // 1024 floats

    normalize_feat<<<1024, 128, 0, stream>>>(features, featb, S, out);
    gemm_lse<<<dim3(XCHUNK, 4), 512, 0, stream>>>(featb, memory, S);
    finalize_k<<<256, 256, 0, stream>>>(featb, memory, labels, S, out);
}